// Round 1
// 170.784 us; speedup vs baseline: 1.0036x; 1.0036x over previous
//
#include <hip/hip_runtime.h>

// FusionLoss: scalar loss over (B=128, J=16, H=128, W=128) inputs.
// Inputs (setup_inputs order):
//   d_in[0] output  float32  [128,16,128,128]
//   d_in[1] mask    int32    [128,16]
//   d_in[2] ind     int32    [128,16]
//   d_in[3] target  float32  [128,16,1]   (also 'visible' in var loss)
//   d_in[4] gt_2d   float32  [128,32]
// Output: scalar float32.
//
// Structure: 1 block x 128 threads (2 waves), one thread per batch.
// Critical path is 2 dependent memory round trips:
//   (1) ind[b,0:16]  -> compute gather addresses
//   (2) 16 scattered gathers from the 128 MiB output tensor
// All other per-batch vectors (target/mask/gt2d) are issued between (1)
// and the vmcnt wait, so they complete inside the gather shadow.
// All per-thread loads are 16 B vectorized: 20 load instrs instead of 80.

#define NB 128
#define NJ 16
#define NH 128
#define NW 128
#define NE 12
#define NG 4

__global__ __launch_bounds__(128) void fusion_loss_kernel(
    const float* __restrict__ output,
    const int*   __restrict__ mask,
    const int*   __restrict__ ind,
    const float* __restrict__ target,
    const float* __restrict__ gt2d,
    float*       __restrict__ out)
{
    const int b = threadIdx.x;            // one thread per batch, 0..127

    // edge tables (compile-time constants; live in SGPRs/inline)
    const int   id1[NE] = {0,1,3,4,10,11,13,14,2,3,12,13};
    const int   id2[NE] = {1,2,4,5,11,12,14,15,6,6,8,8};
    const int   gid[NE] = {0,0,0,0,1,1,1,1,2,2,3,3};
    const float wsk[NE] = {1.0085885098415446f, 1.0f, 1.0f, 1.0085885098415446f,
                           1.1375361376887123f, 1.0f, 1.0f, 1.1375361376887123f,
                           1.0f, 1.0f, 1.0f, 1.0f};

    // ---- phase 1: ind loads FIRST (the gather depends only on these) ----
    union { int4 v[4]; int a[NJ]; } ui;
    {
        const int4* p = reinterpret_cast<const int4*>(ind + b * NJ);
#pragma unroll
        for (int k = 0; k < 4; ++k) ui.v[k] = p[k];
    }

    // independent per-batch vectors: issued after ind, before the vmcnt
    // wait, so they overlap the gather round trip.
    union { float4 v[4]; float a[NJ]; }     ut;   // target / visible
    union { int4   v[4]; int   a[NJ]; }     um;   // mask
    union { float4 v[8]; float a[2 * NJ]; } ug;   // gt_2d
    {
        const float4* pt = reinterpret_cast<const float4*>(target + b * NJ);
        const int4*   pm = reinterpret_cast<const int4*>(mask + b * NJ);
        const float4* pg = reinterpret_cast<const float4*>(gt2d + b * 2 * NJ);
#pragma unroll
        for (int k = 0; k < 4; ++k) ut.v[k] = pt[k];
#pragma unroll
        for (int k = 0; k < 4; ++k) um.v[k] = pm[k];
#pragma unroll
        for (int k = 0; k < 8; ++k) ug.v[k] = pg[k];
    }

    // ---- phase 2: scattered gather ----
    // feat layout: feat[b, h*(W*J) + w*J + j] = output[b, j, h, w]
    //   t = ind value;  j = t & 15;  hw = t >> 4  (= h*W + w)
    const float* ob = output + (size_t)b * (NJ * NH * NW);
    float pred[NJ];
#pragma unroll
    for (int j = 0; j < NJ; ++j) {
        const int t = ui.a[j];
        pred[j] = ob[((t & (NJ - 1)) * (NH * NW)) + (t >> 4)];
    }

    // ---- reg loss partials (mask is zeros in practice; generic compute) ----
    float sl1  = 0.0f;   // smooth-L1 partial sum
    float numm = 0.0f;   // mask count partial
    int   masksum = 0;
#pragma unroll
    for (int j = 0; j < NJ; ++j) {
        const float m  = (float)um.a[j];
        const float d  = pred[j] * m - ut.a[j] * m;
        const float ad = fabsf(d);
        sl1  += (ad < 1.0f) ? 0.5f * d * d : ad - 0.5f;
        numm += m;
        masksum += um.a[j];
    }

    // ---- var loss: 12 edges, 4 groups, all in registers ----
    float gnum[NG] = {0.f, 0.f, 0.f, 0.f};
    float gsum[NG] = {0.f, 0.f, 0.f, 0.f};
    float lv[NE];
    bool  vv[NE];
#pragma unroll
    for (int e = 0; e < NE; ++e) {
        const int a = id1[e], c = id2[e];
        const bool v = (ut.a[a] > 0.5f) && (ut.a[c] > 0.5f);
        const float dx  = ug.a[2 * a]     - ug.a[2 * c];
        const float dy  = ug.a[2 * a + 1] - ug.a[2 * c + 1];
        const float d2d = dx * dx + dy * dy;
        const float dzv = pred[a] - pred[c];
        const float s   = v ? (d2d + dzv * dzv) : 1.0f;
        const float l   = v ? sqrtf(s) * wsk[e] : 0.0f;
        lv[e] = l;
        vv[e] = v;
        gnum[gid[e]] += v ? 1.0f : 0.0f;
        gsum[gid[e]] += l;
    }

    float E[NG];
#pragma unroll
    for (int g = 0; g < NG; ++g)
        E[g] = (gnum[g] >= 0.5f) ? gsum[g] / fmaxf(gnum[g], 1.0f) : 0.0f;

    float tot = 0.0f;
#pragma unroll
    for (int e = 0; e < NE; ++e) {
        if (vv[e]) {
            const float ne = fmaxf(gnum[gid[e]], 1.0f);
            const float dd = lv[e] - E[gid[e]];
            tot += dd * dd / (2.0f * ne);
        }
    }
    // active[b] = (sum_j mask[b,j] == 0)
    if (masksum != 0) tot = 0.0f;

    // ---- reduce sl1, numm, tot across 128 threads (2 waves) ----
#pragma unroll
    for (int off = 32; off > 0; off >>= 1) {
        sl1  += __shfl_down(sl1,  off, 64);
        numm += __shfl_down(numm, off, 64);
        tot  += __shfl_down(tot,  off, 64);
    }
    __shared__ float s_sl1[2], s_num[2], s_tot[2];
    const int wave = threadIdx.x >> 6;
    const int lane = threadIdx.x & 63;
    if (lane == 0) { s_sl1[wave] = sl1; s_num[wave] = numm; s_tot[wave] = tot; }
    __syncthreads();
    if (threadIdx.x == 0) {
        const float S = s_sl1[0] + s_sl1[1];
        const float N = s_num[0] + s_num[1];
        const float T = s_tot[0] + s_tot[1];
        // loss = REG_WEIGHT * sl1/(num+1e-4) + VAR_WEIGHT * total / B
        out[0] = S / (N + 0.0001f) + 0.01f * T / 128.0f;
    }
}

extern "C" void kernel_launch(void* const* d_in, const int* in_sizes, int n_in,
                              void* d_out, int out_size, void* d_ws, size_t ws_size,
                              hipStream_t stream) {
    const float* output = (const float*)d_in[0];
    const int*   mask   = (const int*)  d_in[1];
    const int*   ind    = (const int*)  d_in[2];
    const float* target = (const float*)d_in[3];
    const float* gt2d   = (const float*)d_in[4];
    float*       out    = (float*)d_out;

    fusion_loss_kernel<<<1, 128, 0, stream>>>(output, mask, ind, target, gt2d, out);
}